// Round 1
// baseline (330.190 us; speedup 1.0000x reference)
//
#include <hip/hip_runtime.h>
#include <cstdint>
#include <cstddef>

// Shapes (fixed by the reference problem)
#define D     1024
#define LSEQ  4096
#define BATCH 4
#define MROWS (BATCH * LSEQ)   // 16384 GEMM rows

typedef __attribute__((ext_vector_type(8))) __bf16 bf16x8;
typedef __attribute__((ext_vector_type(4))) float  f32x4;

__device__ __forceinline__ ushort f2bf(float f) {
  union { float f; uint32_t u; } v; v.f = f;
  uint32_t u = v.u;
  // round-to-nearest-even bf16 (inputs are finite randoms; NaN path not needed)
  return (ushort)((u + 0x7fffu + ((u >> 16) & 1u)) >> 16);
}

__device__ __forceinline__ float silu_f(float x) { return x / (1.f + expf(-x)); }

// ---------------------------------------------------------------------------
// Kernel A: Wp (f32, [D][D]) -> bf16
// ---------------------------------------------------------------------------
__global__ __launch_bounds__(256) void cvt_wp(const float* __restrict__ s,
                                              ushort* __restrict__ d) {
  const int i = (blockIdx.x * 256 + threadIdx.x) * 4;   // D*D / 4 threads
  const float4 v = *reinterpret_cast<const float4*>(&s[i]);
  ushort4 o;
  o.x = f2bf(v.x); o.y = f2bf(v.y); o.z = f2bf(v.z); o.w = f2bf(v.w);
  *reinterpret_cast<ushort4*>(&d[i]) = o;
}

// ---------------------------------------------------------------------------
// Kernel B: h = silu(causal_dwconv_k3(u, w1, b1)); also emit u as bf16 (GEMM A)
// grid (D/256, LSEQ/TL1, BATCH), 256 threads; thread owns one channel, TL1 rows
// ---------------------------------------------------------------------------
#define TL1 64
__global__ __launch_bounds__(256) void conv1_silu_cvt(
    const float* __restrict__ u, const float* __restrict__ w1,
    const float* __restrict__ b1, float* __restrict__ h,
    ushort* __restrict__ ubf) {
  const int c  = blockIdx.x * 256 + threadIdx.x;
  const int b  = blockIdx.z;
  const int l0 = blockIdx.y * TL1;
  const size_t base = ((size_t)b * LSEQ) * D + c;
  const float wa = w1[c], wb = w1[D + c], wcc = w1[2 * D + c];
  const float bias = b1[c];
  // causal: u[l<0] = 0
  float x0 = (l0 >= 2) ? u[base + (size_t)(l0 - 2) * D] : 0.f;
  float x1 = (l0 >= 1) ? u[base + (size_t)(l0 - 1) * D] : 0.f;
  #pragma unroll 4
  for (int l = l0; l < l0 + TL1; ++l) {
    const float x2 = u[base + (size_t)l * D];
    const float v = fmaf(x0, wa, fmaf(x1, wb, fmaf(x2, wcc, bias)));
    h[base + (size_t)l * D]   = silu_f(v);
    ubf[base + (size_t)l * D] = f2bf(x2);
    x0 = x1; x1 = x2;
  }
}

// ---------------------------------------------------------------------------
// Kernel C: proj = silu(u @ Wp^T + bp)  via bf16 MFMA, fp32 accumulate.
// A = ubf [MROWS][D] bf16 row-major (K contiguous)
// B = wpbf [D][D]    bf16 row-major (K contiguous)  -> C = A * B^T
// 128x128 tile, BK=32, 256 threads = 4 waves in 2x2, 4x4 frags of 16x16/wave.
// Fragment layouts per learn_hip m89/m92: A/B lane l holds 8 contiguous K at
// row (l&15), k-base 8*(l>>4); C/D: col = lane&15, row = (lane>>4)*4 + reg.
// ---------------------------------------------------------------------------
#define BM 128
#define BN 128
#define BK 32
__global__ __launch_bounds__(256) void gemm_bias_silu(
    const ushort* __restrict__ A, const ushort* __restrict__ B,
    const float* __restrict__ bp, float* __restrict__ out) {
  __shared__ ushort lsA[BM][BK];   // 8 KiB
  __shared__ ushort lsB[BN][BK];   // 8 KiB
  const int tid  = threadIdx.x;
  const int wave = tid >> 6, lane = tid & 63;
  const int m0 = blockIdx.x * BM;
  const int n0 = blockIdx.y * BN;
  const int wr = (wave >> 1) * 64;   // wave row offset in tile
  const int wc = (wave & 1) * 64;    // wave col offset in tile
  const int fr = lane & 15;          // fragment row (M or N index)
  const int fk = (lane >> 4) * 8;    // fragment k base
  // staging: 512 chunks of 8 bf16 per tile; thread does chunks tid and tid+256
  const int row0 = tid >> 2,         col0 = (tid & 3) * 8;
  const int row1 = (tid + 256) >> 2, col1 = col0;

  f32x4 acc[4][4];
  #pragma unroll
  for (int i = 0; i < 4; ++i)
    #pragma unroll
    for (int j = 0; j < 4; ++j) acc[i][j] = f32x4{0.f, 0.f, 0.f, 0.f};

  for (int k0 = 0; k0 < D; k0 += BK) {
    *reinterpret_cast<int4*>(&lsA[row0][col0]) =
        *reinterpret_cast<const int4*>(&A[(size_t)(m0 + row0) * D + k0 + col0]);
    *reinterpret_cast<int4*>(&lsA[row1][col1]) =
        *reinterpret_cast<const int4*>(&A[(size_t)(m0 + row1) * D + k0 + col1]);
    *reinterpret_cast<int4*>(&lsB[row0][col0]) =
        *reinterpret_cast<const int4*>(&B[(size_t)(n0 + row0) * D + k0 + col0]);
    *reinterpret_cast<int4*>(&lsB[row1][col1]) =
        *reinterpret_cast<const int4*>(&B[(size_t)(n0 + row1) * D + k0 + col1]);
    __syncthreads();
    bf16x8 af[4], bfr[4];
    #pragma unroll
    for (int i = 0; i < 4; ++i)
      af[i] = *reinterpret_cast<const bf16x8*>(&lsA[wr + i * 16 + fr][fk]);
    #pragma unroll
    for (int j = 0; j < 4; ++j)
      bfr[j] = *reinterpret_cast<const bf16x8*>(&lsB[wc + j * 16 + fr][fk]);
    #pragma unroll
    for (int i = 0; i < 4; ++i)
      #pragma unroll
      for (int j = 0; j < 4; ++j)
        acc[i][j] = __builtin_amdgcn_mfma_f32_16x16x32_bf16(af[i], bfr[j],
                                                            acc[i][j], 0, 0, 0);
    __syncthreads();
  }
  // epilogue: +bias, silu, store fp32
  const int ccol  = lane & 15;
  const int rbase = (lane >> 4) * 4;
  #pragma unroll
  for (int i = 0; i < 4; ++i) {
    #pragma unroll
    for (int j = 0; j < 4; ++j) {
      const int gn  = n0 + wc + j * 16 + ccol;
      const float bv = bp[gn];
      #pragma unroll
      for (int r = 0; r < 4; ++r) {
        const int gm = m0 + wr + i * 16 + rbase + r;
        out[(size_t)gm * D + gn] = silu_f(acc[i][j][r] + bv);
      }
    }
  }
}

// ---------------------------------------------------------------------------
// Kernel D: out = (causal_dwconv_k128(h, w2) + b2) * proj   (proj in-place in out)
// Output-stationary: thread owns 1 channel, RL=16 outputs/group, rolling 31-reg
// h window; 8 tap-blocks of 16. Per output ~9 h loads (L1/L2) + 128 FMA.
// grid (D/256, LSEQ/TL4, BATCH), 256 threads.
// ---------------------------------------------------------------------------
#define TL4 64
#define RL  16
__global__ __launch_bounds__(256) void conv2_mul(
    const float* __restrict__ h, const float* __restrict__ w2,
    const float* __restrict__ b2, float* __restrict__ out) {
  const int c  = blockIdx.x * 256 + threadIdx.x;
  const int b  = blockIdx.z;
  const int L0 = blockIdx.y * TL4;
  const float* hb  = h   + ((size_t)b * LSEQ) * D + c;
  float*       ob  = out + ((size_t)b * LSEQ) * D + c;
  const float* w2c = w2 + c;
  const float bias = b2[c];

  for (int g = 0; g < TL4 / RL; ++g) {
    const int L = L0 + g * RL;
    float acc[RL];
    #pragma unroll
    for (int r = 0; r < RL; ++r) acc[r] = 0.f;

    float hh[31];
    int jb = L - 127;                         // window base (block-uniform)
    #pragma unroll
    for (int q = 0; q < 31; ++q) {
      const int j = jb + q;
      hh[q] = (j >= 0) ? hb[(size_t)j * D] : 0.f;   // scalar-uniform guard
    }
    #pragma unroll
    for (int tb = 0; tb < 8; ++tb) {
      #pragma unroll
      for (int i = 0; i < 16; ++i) {
        const float wv = w2c[(size_t)(tb * 16 + i) * D];
        #pragma unroll
        for (int r = 0; r < RL; ++r)
          acc[r] = fmaf(wv, hh[i + r], acc[r]);
      }
      if (tb < 7) {
        jb += 16;
        #pragma unroll
        for (int q = 0; q < 15; ++q) hh[q] = hh[q + 16];
        #pragma unroll
        for (int q = 15; q < 31; ++q) {
          const int j = jb + q;
          hh[q] = (j >= 0) ? hb[(size_t)j * D] : 0.f;
        }
      }
    }
    #pragma unroll
    for (int r = 0; r < RL; ++r) {
      const size_t p = (size_t)(L + r);
      const float pj = ob[p * D];              // proj (read before overwrite)
      ob[p * D] = (acc[r] + bias) * pj;
    }
  }
}

// ---------------------------------------------------------------------------
// Workspace layout (needs ~98.1 MiB):
//   h    : f32  [4][4096][1024]  @ 0          (64 MiB)
//   ubf  : bf16 [16384][1024]    @ 67108864   (32 MiB)
//   wpbf : bf16 [1024][1024]     @ 100663296  ( 2 MiB)
// proj lives in d_out (GEMM writes it; conv2_mul multiplies in place).
// ---------------------------------------------------------------------------
extern "C" void kernel_launch(void* const* d_in, const int* in_sizes, int n_in,
                              void* d_out, int out_size, void* d_ws,
                              size_t ws_size, hipStream_t stream) {
  const float* u  = (const float*)d_in[0];
  const float* w1 = (const float*)d_in[1];
  const float* b1 = (const float*)d_in[2];
  const float* w2 = (const float*)d_in[3];
  const float* b2 = (const float*)d_in[4];
  const float* Wp = (const float*)d_in[5];
  const float* bp = (const float*)d_in[6];
  float* out = (float*)d_out;

  char* ws = (char*)d_ws;
  float*  h    = (float*)(ws);
  ushort* ubf  = (ushort*)(ws + (size_t)67108864);
  ushort* wpbf = (ushort*)(ws + (size_t)100663296);

  cvt_wp<<<dim3(D * D / 1024), 256, 0, stream>>>(Wp, wpbf);
  conv1_silu_cvt<<<dim3(D / 256, LSEQ / TL1, BATCH), 256, 0, stream>>>(
      u, w1, b1, h, ubf);
  gemm_bias_silu<<<dim3(MROWS / BM, D / BN), 256, 0, stream>>>(
      ubf, wpbf, bp, out);
  conv2_mul<<<dim3(D / 256, LSEQ / TL4, BATCH), 256, 0, stream>>>(
      h, w2, b2, out);
}